// Round 8
// baseline (114.948 us; speedup 1.0000x reference)
//
#include <hip/hip_runtime.h>
#include <math.h>

// LRU (Laguerre ladder) recurrence, MI355X — two-pass checkpoint/recompute.
// B=32, T=512, I=64, F=64, H=64. Output: (B,T,F,H) f32 ++ h_final (F,B,H) f32.
//
// Pass 1 (2048 blocks x 64 thr, no LDS): per (b,f) chain, compute u[t] (r6
// GEMM), run the skewed recurrence in registers, capture checkpoints
// y[64c-1] (c=1..7) + h_final; store u and checkpoints to ws.
// Pass 2 (512 blocks x 256 thr = 4 waves): block = (b, f-half, t-chunk).
// 32 chains, 8 lanes/chain (lane j owns h=8j..8j+7, skew span 8). Seed from
// checkpoint, recompute 64 t-rows into a 16-slot x 8KB LDS ring, flush 4
// complete out-rows per superstep as fully-sequential 1KB-per-instr stores.
#define TT 512
#define FF 64
#define BB 32
#define HH 64

// ---------------- common DPP helpers ----------------
// full-wave shift lane l-1 -> l (pass 1: 1 chain across 64 lanes)
__device__ __forceinline__ float shift_up1(float v, int j16) {
    int s1 = __builtin_amdgcn_update_dpp(0, __float_as_int(v), 0x111, 0xf, 0xf, true);  // row_shr:1
    int s2 = __builtin_amdgcn_update_dpp(0, __float_as_int(v), 0x142, 0xf, 0xf, false); // row_bcast:15
    return __int_as_float((j16 == 0) ? s2 : s1);
}
// 16-lane-row shift (pass 2: j-groups of 8; cross-group leakage lands on j==0
// lanes which take the u path instead)
__device__ __forceinline__ float dpp_row_shr1(float v) {
    int r = __builtin_amdgcn_update_dpp(0, __float_as_int(v), 0x111, 0xf, 0xf, true);
    return __int_as_float(r);
}

// ======================= PASS 1 =======================
// K is a compile-time literal after unrolling.
#define P1STEP(K) do {                                                  \
    const int ci_ = ((K) >> 6) > 7 ? 7 : ((K) >> 6);                    \
    const float uk_ = __int_as_float(__builtin_amdgcn_readlane(         \
        __float_as_int(ua[ci_]), (K) & 63));                            \
    const float shifted_ = shift_up1(vlast, j16);                       \
    const float nbr_cur_ = isl0 ? uk_ : shifted_;                       \
    float v_ = fmaf(cA, nbr_cur_, fmaf(a, prev, -nbr_prev));            \
    const bool live_ = ((unsigned)t < (unsigned)TT);                    \
    v_ = live_ ? v_ : prev;                                             \
    if ((K) >= 63 && (K) <= 510) {                                      \
        const int cc_ = ((K) + 1) >> 6;                                 \
        if (l == (K) - (cc_ << 6) + 1) ck[cc_ - 1] = v_;                \
    }                                                                   \
    nbr_prev = isl0 ? 0.f : nbr_cur_;                                   \
    prev = v_; vlast = v_;                                              \
    ++t;                                                                \
} while (0)

#define P1HALF(BASE) do {                                               \
    _Pragma("unroll")                                                   \
    for (int i_ = 0; i_ < 32; ++i_) { P1STEP((BASE) + i_); }            \
} while (0)

__global__ __launch_bounds__(64) void lru_pass1(
    const float* __restrict__ x,      // (B,T,I)
    const float* __restrict__ W,      // (F,I)
    const float* __restrict__ relax,  // (F,)
    float* __restrict__ out,          // h_final section written here
    float* __restrict__ ws_u,         // (B*F, 512)  u[t]
    float* __restrict__ ws_ck)        // (B*F, 8, 64) checkpoints y[64c-1]
{
    const int w = blockIdx.x;             // 2048: (b,f)
    const int b = w >> 6;
    const int f = w & 63;
    const int l = threadIdx.x;            // hidden index
    const int j16 = l & 15;

    // u[c*64+l] = dot(x[b,c*64+l,:], W[f,:]) into 8 VGPRs (r6-verified)
    float ua[8];
    {
        const float4* __restrict__ Wv = reinterpret_cast<const float4*>(W) + (size_t)f * 16;
        float4 wreg[16];
        #pragma unroll
        for (int q = 0; q < 16; ++q) wreg[q] = Wv[q];
        const float4* __restrict__ xb = reinterpret_cast<const float4*>(x) + (size_t)b * TT * 16;
        #pragma unroll
        for (int c = 0; c < 8; ++c) {
            const int tt = (c << 6) + l;
            const float4* xv = xb + (size_t)tt * 16;
            float acc = 0.f;
            #pragma unroll
            for (int q = 0; q < 16; ++q) {
                const float4 xq = xv[q], wq = wreg[q];
                acc = fmaf(xq.x, wq.x, fmaf(xq.y, wq.y, fmaf(xq.z, wq.z, fmaf(xq.w, wq.w, acc))));
            }
            ua[c] = acc;
        }
    }

    const float rel = relax[f];
    const float a  = sqrtf(rel);
    const float gn = sqrtf(1.0f - rel);
    const bool isl0 = (l == 0);
    const float cA = isl0 ? gn : a;

    float prev = 0.f, nbr_prev = 0.f, vlast = 0.f;
    float ck[7];
    int t = -l;

    P1HALF(0);   P1HALF(32);  P1HALF(64);  P1HALF(96);
    P1HALF(128); P1HALF(160); P1HALF(192); P1HALF(224);
    P1HALF(256); P1HALF(288); P1HALF(320); P1HALF(352);
    P1HALF(384); P1HALF(416); P1HALF(448); P1HALF(480);
    P1HALF(512); P1HALF(544);

    const size_t chain = (size_t)b * 64 + f;
    float* uw = ws_u + chain * 512;
    #pragma unroll
    for (int c = 0; c < 8; ++c) uw[(c << 6) + l] = ua[c];
    float* cw = ws_ck + chain * 512;
    cw[l] = 0.f;                           // c=0 seed = zeros
    #pragma unroll
    for (int c = 1; c < 8; ++c) cw[(c << 6) + l] = ck[c - 1];

    // h_final = y[T-1][l] (frozen in prev; r6-verified)
    out[(size_t)BB * TT * FF * HH + ((size_t)f * BB + b) * HH + l] = prev;
}

// ======================= PASS 2 =======================
__global__ __launch_bounds__(256) void lru_pass2(
    const float* __restrict__ ws_u,
    const float* __restrict__ ws_ck,
    const float* __restrict__ relax,
    float* __restrict__ out)
{
    __shared__ float ring[16 * 2048];     // 16 slots x 8KB = 128KB
    __shared__ float u2[32 * 68];         // u slab, 8.7KB (stride 68 banks-spread)

    const int bid = blockIdx.x;           // 512: (b, fg, tc)
    const int tc = bid & 7;
    const int fg = (bid >> 3) & 1;
    const int b  = bid >> 4;
    const int t0 = tc << 6;
    const int f0 = fg << 5;
    const int tid  = threadIdx.x;
    const int wv   = tid >> 6;
    const int lane = tid & 63;
    const int g = lane >> 3;              // chain within wave
    const int j = lane & 7;               // position in chain (h = 8j..8j+7)
    const int fl = (wv << 3) | g;         // chain within block, 0..31
    const size_t chain = (size_t)b * 64 + f0 + fl;

    // load u slab: u2[fl][0..63] = u[chain][t0..t0+63]
    #pragma unroll
    for (int q = 0; q < 2; ++q) {
        const int idx  = (q << 8) + tid;  // 0..511 float4s
        const int flr  = idx >> 4;
        const int part = idx & 15;
        const float4 v = *(const float4*)(ws_u + ((size_t)b * 64 + f0 + flr) * 512
                                               + t0 + (part << 2));
        *(float4*)(u2 + flr * 68 + (part << 2)) = v;
    }

    const float rel = relax[f0 + fl];
    const float a  = sqrtf(rel);
    const float gn = sqrtf(1.0f - rel);
    const bool isj0 = (j == 0);
    const float cA = isj0 ? gn : a;

    // seed state = y[t0-1] from checkpoint
    const float* sp = ws_ck + chain * 512 + (tc << 6) + (j << 3);
    const float4 s0 = *(const float4*)(sp);
    const float4 s1 = *(const float4*)(sp + 4);
    float p0 = s0.x, p1 = s0.y, p2 = s0.z, p3 = s0.w;
    float p4 = s1.x, p5 = s1.y, p6 = s1.z, p7 = s1.w;
    float vlast = p7;                     // y[t0-1][8j+7] feeds lane j+1's ramp
    float nbr_prev = 0.f;                 // set from shifted during frozen ramp

    const int uoff  = fl * 68;
    const int vbase = (fl << 8) + (j << 5);          // byte offset in a ring row
    const int vtop  = (16 << 13) + vbase;
    int vaddr = (((16 - j) & 15) << 13) + vbase;     // slot (t mod 16)

    __syncthreads();

    int k = 0;
    for (int s = 0; s < 18; ++s) {
        // ---- compute 4 STEPs (k, rows t = t0 + k - j) ----
        #pragma unroll
        for (int ii = 0; ii < 4; ++ii) {
            const int tt = k - j;
            const float uk = u2[uoff + (k & 63)];
            const float shifted = dpp_row_shr1(vlast);
            const float nbr_cur = isj0 ? uk : shifted;
            float n0 = fmaf(cA, nbr_cur, fmaf(a, p0, -nbr_prev));
            float n1 = fmaf(a, n0, fmaf(a, p1, -p0));
            float n2 = fmaf(a, n1, fmaf(a, p2, -p1));
            float n3 = fmaf(a, n2, fmaf(a, p3, -p2));
            float n4 = fmaf(a, n3, fmaf(a, p4, -p3));
            float n5 = fmaf(a, n4, fmaf(a, p5, -p4));
            float n6 = fmaf(a, n5, fmaf(a, p6, -p5));
            float n7 = fmaf(a, n6, fmaf(a, p7, -p6));
            const bool live = ((unsigned)tt < 64u);
            n0 = live ? n0 : p0;  n1 = live ? n1 : p1;
            n2 = live ? n2 : p2;  n3 = live ? n3 : p3;
            n4 = live ? n4 : p4;  n5 = live ? n5 : p5;
            n6 = live ? n6 : p6;  n7 = live ? n7 : p7;
            if (live) {
                float4 w0; w0.x = n0; w0.y = n1; w0.z = n2; w0.w = n3;
                float4 w1; w1.x = n4; w1.y = n5; w1.z = n6; w1.w = n7;
                *(float4*)((char*)ring + vaddr)      = w0;
                *(float4*)((char*)ring + vaddr + 16) = w1;
            }
            vaddr += 8192; vaddr = (vaddr == vtop) ? vbase : vaddr;
            nbr_prev = isj0 ? 0.f : nbr_cur;
            p0 = n0; p1 = n1; p2 = n2; p3 = n3;
            p4 = n4; p5 = n5; p6 = n6; p7 = n7;
            vlast = n7;
            ++k;
        }
        __syncthreads();
        // ---- flush band: rows [4s-8 .. 4s-5], one full 8KB row per wave ----
        if (s >= 2) {
            const int rr = ((s << 2) - 8) + wv;
            const float* rp = ring + ((rr & 15) << 11) + (lane << 2);
            float* op = out + (((size_t)((b << 9) + t0 + rr)) << 12)
                            + (fg << 11) + (lane << 2);
            float4 q0 = *(const float4*)(rp + 0 * 256);
            float4 q1 = *(const float4*)(rp + 1 * 256);
            float4 q2 = *(const float4*)(rp + 2 * 256);
            float4 q3 = *(const float4*)(rp + 3 * 256);
            float4 q4 = *(const float4*)(rp + 4 * 256);
            float4 q5 = *(const float4*)(rp + 5 * 256);
            float4 q6 = *(const float4*)(rp + 6 * 256);
            float4 q7 = *(const float4*)(rp + 7 * 256);
            *(float4*)(op + 0 * 256) = q0;
            *(float4*)(op + 1 * 256) = q1;
            *(float4*)(op + 2 * 256) = q2;
            *(float4*)(op + 3 * 256) = q3;
            *(float4*)(op + 4 * 256) = q4;
            *(float4*)(op + 5 * 256) = q5;
            *(float4*)(op + 6 * 256) = q6;
            *(float4*)(op + 7 * 256) = q7;
        }
    }
}

// ======================= FALLBACK (r6, verified 81.6us) =======================
#define NSLOT 96
#define RSF 64
#define STEP(MASKED) do {                                              \
    const float uk_ = __int_as_float(__builtin_amdgcn_readlane(        \
        __float_as_int(UREG_), LIDX_));                                \
    const float shifted_ = shift_up1(vlast, j16);                      \
    const float nbr_cur_ = isj0 ? uk_ : shifted_;                      \
    float v_ = fmaf(cA, nbr_cur_, fmaf(a, prev, -nbr_prev));           \
    if (MASKED) {                                                      \
        const bool live_ = ((unsigned)t < (unsigned)TT);               \
        v_ = live_ ? v_ : prev;                                        \
        if (live_) *(float*)((char*)ring + vaddr) = v_;                \
    } else {                                                           \
        *(float*)((char*)ring + vaddr) = v_;                           \
    }                                                                  \
    vaddr += 256; vaddr = (vaddr == vtop) ? vbase : vaddr;             \
    nbr_prev = isj0 ? 0.f : nbr_cur_;                                  \
    prev = v_; vlast = v_;                                             \
    ++t;                                                               \
} while (0)
#define READS(G0, G1, G2, G3, OPP) do {                                \
    const float* rp_ = ring + (sb + (l >> 4)) * RSF + (j16 << 2);      \
    G0 = *(const float4*)(rp_ + 0 * 4 * RSF);                          \
    G1 = *(const float4*)(rp_ + 1 * 4 * RSF);                          \
    G2 = *(const float4*)(rp_ + 2 * 4 * RSF);                          \
    G3 = *(const float4*)(rp_ + 3 * 4 * RSF);                          \
    OPP = ochunk + ((size_t)(l >> 4) << 12) + (j16 << 2);              \
    ochunk += 16 * 4096;                                               \
    sb += 16; if (sb == NSLOT) sb = 0;                                 \
} while (0)
#define STORES(G0, G1, G2, G3, OPP) do {                               \
    *(float4*)(OPP + (size_t)0 * 16384) = G0;                          \
    *(float4*)(OPP + (size_t)1 * 16384) = G1;                          \
    *(float4*)(OPP + (size_t)2 * 16384) = G2;                          \
    *(float4*)(OPP + (size_t)3 * 16384) = G3;                          \
} while (0)
#define PT_RD_A do { READS(gA0,gA1,gA2,gA3, opA); } while (0)
#define PT_AB   do { STORES(gA0,gA1,gA2,gA3, opA); READS(gB0,gB1,gB2,gB3, opB); } while (0)
#define PT_BA   do { STORES(gB0,gB1,gB2,gB3, opB); READS(gA0,gA1,gA2,gA3, opA); } while (0)
#define NOPT    do {} while (0)
#define HALF(UREG, HS, MASKED, P6, P22) do {                           \
    const float UREG_ = (UREG);                                        \
    _Pragma("unroll")                                                  \
    for (int i_ = 0; i_ < 32; ++i_) {                                  \
        const int LIDX_ = (HS) * 32 + i_;                              \
        STEP(MASKED);                                                  \
        if (i_ == 6)  { P6; }                                          \
        if (i_ == 22) { P22; }                                         \
    }                                                                  \
} while (0)
#define PAIR_STEADY(UREG) do {                                         \
    HALF(UREG, 0, false, PT_AB, PT_BA);                                \
    HALF(UREG, 1, false, PT_AB, PT_BA);                                \
} while (0)

__global__ __launch_bounds__(64) void lru_fallback(
    const float* __restrict__ x, const float* __restrict__ W,
    const float* __restrict__ relax, float* __restrict__ out)
{
    __shared__ float ring[NSLOT * RSF];
    const int w = blockIdx.x;
    const int b = w >> 6;
    const int f = w & 63;
    const int l = threadIdx.x;
    const int j16 = l & 15;
    float ua[8];
    {
        const float4* __restrict__ Wv = reinterpret_cast<const float4*>(W) + (size_t)f * 16;
        float4 wreg[16];
        #pragma unroll
        for (int q = 0; q < 16; ++q) wreg[q] = Wv[q];
        const float4* __restrict__ xb = reinterpret_cast<const float4*>(x) + (size_t)b * TT * 16;
        #pragma unroll
        for (int c = 0; c < 8; ++c) {
            const int tt = (c << 6) + l;
            const float4* xv = xb + (size_t)tt * 16;
            float acc = 0.f;
            #pragma unroll
            for (int q = 0; q < 16; ++q) {
                const float4 xq = xv[q], wq = wreg[q];
                acc = fmaf(xq.x, wq.x, fmaf(xq.y, wq.y, fmaf(xq.z, wq.z, fmaf(xq.w, wq.w, acc))));
            }
            ua[c] = acc;
        }
    }
    const float rel = relax[f];
    const float a  = sqrtf(rel);
    const float gn = sqrtf(1.0f - rel);
    const bool isj0 = (l == 0);
    const float cA = isj0 ? gn : a;
    float prev = 0.f, nbr_prev = 0.f, vlast = 0.f;
    int t = -l;
    const int vbase = l << 2;
    const int vtop  = NSLOT * 256 + vbase;
    int vaddr = ((NSLOT - l) % NSLOT) * 256 + vbase;
    int sb = 0;
    float* ochunk = out + (size_t)b * (TT * FF * HH) + (size_t)f * HH;
    float4 gA0, gA1, gA2, gA3, gB0, gB1, gB2, gB3;
    float *opA = nullptr, *opB = nullptr;
    HALF(ua[0], 0, true, NOPT, NOPT);
    HALF(ua[0], 1, true, NOPT, NOPT);
    HALF(ua[1], 0, false, NOPT, PT_RD_A);
    HALF(ua[1], 1, false, PT_AB, PT_BA);
    PAIR_STEADY(ua[2]);
    PAIR_STEADY(ua[3]);
    PAIR_STEADY(ua[4]);
    PAIR_STEADY(ua[5]);
    PAIR_STEADY(ua[6]);
    PAIR_STEADY(ua[7]);
    HALF(ua[7], 0, true, PT_AB, PT_BA);
    HALF(ua[7], 1, true, PT_AB, PT_BA);
    STORES(gA0, gA1, gA2, gA3, opA);
    READS(gB0, gB1, gB2, gB3, opB);
    STORES(gB0, gB1, gB2, gB3, opB);
    out[(size_t)BB * TT * FF * HH + ((size_t)f * BB + b) * HH + l] = prev;
}

extern "C" void kernel_launch(void* const* d_in, const int* in_sizes, int n_in,
                              void* d_out, int out_size, void* d_ws, size_t ws_size,
                              hipStream_t stream) {
    const float* x     = (const float*)d_in[0];
    const float* W     = (const float*)d_in[1];
    const float* relax = (const float*)d_in[2];
    float* out = (float*)d_out;
    const size_t need = (size_t)2048 * 512 * 4 * 2;   // u (4MB) + checkpoints (4MB)
    if (ws_size >= need) {
        float* ws_u  = (float*)d_ws;
        float* ws_ck = ws_u + (size_t)2048 * 512;
        lru_pass1<<<dim3(2048), dim3(64), 0, stream>>>(x, W, relax, out, ws_u, ws_ck);
        lru_pass2<<<dim3(512), dim3(256), 0, stream>>>(ws_u, ws_ck, relax, out);
    } else {
        lru_fallback<<<dim3(2048), dim3(64), 0, stream>>>(x, W, relax, out);
    }
}

// Round 9
// 87.435 us; speedup vs baseline: 1.3147x; 1.3147x over previous
//
#include <hip/hip_runtime.h>
#include <math.h>

// LRU (Laguerre ladder) recurrence, MI355X.
// B=32, T=512, I=64, F=64, H=64. Output: (B,T,F,H) f32 ++ h_final (F,B,H) f32.
// One (b,f) chain per 64-lane wave; lane l owns hidden index l; wavefront-skew
// over t (lane l computes row t = k - l at global step k).
// Ring: 96 slots x 64 floats = 24 KB LDS -> 6 blocks/CU.
// Flush: 16-row chunks; chunk q is ds_read at k = 16q+86 (margin 8 after lane-63
// completes row 16q+15 at k=16q+78; margin 10 before slot reuse at k=16q+96),
// stored to HBM 16 STEPs later via ping-pong register sets A/B.
// u[] lives in 8 VGPRs, broadcast by readlane with compile-time pair index.
//
// r9 change vs r6 (verified 81.6us): XCD-aware block swizzle. All 64 f-blocks
// of a batch b map to the same XCD (hw round-robin assumption xcd = blockIdx%8,
// m157 bijective form, 2048%8==0). Their 64x256B contributions to each 16KB
// out t-row then aggregate densely in that XCD's L2 before HBM eviction,
// turning scattered 256B@16KB-stride write granules into dense row evictions.
#define TT 512
#define FF 64
#define BB 32
#define HH 64
#define NSLOT 96
#define RSF 64                       // floats per ring row

__device__ __forceinline__ float shift_up1(float v, int j16) {
    // lane l gets lane l-1's value across the whole wave
    int s1 = __builtin_amdgcn_update_dpp(0, __float_as_int(v), 0x111, 0xf, 0xf, true);  // row_shr:1
    int s2 = __builtin_amdgcn_update_dpp(0, __float_as_int(v), 0x142, 0xf, 0xf, false); // row_bcast:15
    return __int_as_float((j16 == 0) ? s2 : s1);
}

// one recurrence step; MASKED is a compile-time literal
#define STEP(MASKED, UK) do {                                          \
    const float shifted_ = shift_up1(vlast, j16);                      \
    const float nbr_cur_ = isj0 ? (UK) : shifted_;                     \
    float v_ = fmaf(cA, nbr_cur_, fmaf(a, prev, -nbr_prev));           \
    if (MASKED) {                                                      \
        const bool live_ = ((unsigned)t < (unsigned)TT);               \
        v_ = live_ ? v_ : prev;                                        \
        if (live_) *(float*)((char*)ring + vaddr) = v_;                \
    } else {                                                           \
        *(float*)((char*)ring + vaddr) = v_;                           \
    }                                                                  \
    vaddr += 256; vaddr = (vaddr == vtop) ? vbase : vaddr;             \
    nbr_prev = isj0 ? 0.f : nbr_cur_;                                  \
    prev = v_; vlast = v_;                                             \
    ++t;                                                               \
} while (0)

// read next chunk (16 rows) from ring into a float4 set + capture its out ptr.
// Register i holds row (l>>4) + 4*i of the chunk, cols 4*j16..4*j16+3.
#define READS(G0, G1, G2, G3, OPP) do {                                \
    const float* rp_ = ring + (sb + (l >> 4)) * RSF + (j16 << 2);      \
    G0 = *(const float4*)(rp_ + 0 * 4 * RSF);                          \
    G1 = *(const float4*)(rp_ + 1 * 4 * RSF);                          \
    G2 = *(const float4*)(rp_ + 2 * 4 * RSF);                          \
    G3 = *(const float4*)(rp_ + 3 * 4 * RSF);                          \
    OPP = ochunk + ((size_t)(l >> 4) << 12) + (j16 << 2);              \
    ochunk += 16 * 4096;                                               \
    sb += 16; if (sb == NSLOT) sb = 0;                                 \
} while (0)

// register i goes to t = chunk_base + (l>>4) + 4*i  (out t-stride = 4096 floats)
#define STORES(G0, G1, G2, G3, OPP) do {                               \
    *(float4*)(OPP + (size_t)0 * 16384) = G0;                          \
    *(float4*)(OPP + (size_t)1 * 16384) = G1;                          \
    *(float4*)(OPP + (size_t)2 * 16384) = G2;                          \
    *(float4*)(OPP + (size_t)3 * 16384) = G3;                          \
} while (0)

#define PT_RD_A do { READS(gA0,gA1,gA2,gA3, opA); } while (0)
#define PT_AB   do { STORES(gA0,gA1,gA2,gA3, opA); READS(gB0,gB1,gB2,gB3, opB); } while (0)
#define PT_BA   do { STORES(gB0,gB1,gB2,gB3, opB); READS(gA0,gA1,gA2,gA3, opA); } while (0)
#define NOPT    do {} while (0)

// one 32-STEP half; flush points after STEP i_=6 and i_=22 (k = 16q+86 pattern)
#define HALF(UREG, HS, MASKED, P6, P22) do {                           \
    _Pragma("unroll")                                                  \
    for (int i_ = 0; i_ < 32; ++i_) {                                  \
        const float uk_ = __int_as_float(                              \
            __builtin_amdgcn_readlane(__float_as_int(UREG), (HS) * 32 + i_)); \
        STEP(MASKED, uk_);                                             \
        if (i_ == 6)  { P6; }                                          \
        if (i_ == 22) { P22; }                                         \
    }                                                                  \
} while (0)

// steady pair: 4 flush points, uniform {store A, read B} / {store B, read A}
#define PAIR_STEADY(UREG) do {                                         \
    HALF(UREG, 0, false, PT_AB, PT_BA);                                \
    HALF(UREG, 1, false, PT_AB, PT_BA);                                \
} while (0)

__global__ __launch_bounds__(64) void lru_kernel(
    const float* __restrict__ x,      // (B,T,I)
    const float* __restrict__ W,      // (F,I)
    const float* __restrict__ relax,  // (F,)
    float* __restrict__ out)          // (B,T,F,H) ++ (F,B,H)
{
    __shared__ float ring[NSLOT * RSF];   // 24576 B -> 6 blocks/CU

    // XCD-aware swizzle (m157 bijective form, nwg=2048, 2048%8==0, cpx=256):
    // xcd = blockIdx.x % 8 owns logical ids [xcd*256, xcd*256+256)
    // = batches b in [4*xcd, 4*xcd+4) with ALL 64 f's -> dense 16KB-row
    // aggregation in that XCD's L2.
    const int w0 = blockIdx.x;
    const int w  = (w0 & 7) * 256 + (w0 >> 3);   // logical (b,f) id
    const int b = w >> 6;
    const int f = w & 63;
    const int l = threadIdx.x;            // hidden index owned by this lane
    const int j16 = l & 15;

    // ---------- phase 1: u[c*64+l] = dot(x[b,c*64+l,:], W[f,:]) into 8 VGPRs ----------
    float ua[8];
    {
        const float4* __restrict__ Wv = reinterpret_cast<const float4*>(W) + (size_t)f * 16;
        float4 wreg[16];
        #pragma unroll
        for (int q = 0; q < 16; ++q) wreg[q] = Wv[q];
        const float4* __restrict__ xb = reinterpret_cast<const float4*>(x) + (size_t)b * TT * 16;
        #pragma unroll
        for (int c = 0; c < 8; ++c) {
            const int tt = (c << 6) + l;
            const float4* xv = xb + (size_t)tt * 16;
            float acc = 0.f;
            #pragma unroll
            for (int q = 0; q < 16; ++q) {
                const float4 xq = xv[q], wq = wreg[q];
                acc = fmaf(xq.x, wq.x, fmaf(xq.y, wq.y, fmaf(xq.z, wq.z, fmaf(xq.w, wq.w, acc))));
            }
            ua[c] = acc;
        }
    }

    // ---------- phase 2: skewed recurrence ----------
    const float rel = relax[f];
    const float a  = sqrtf(rel);
    const float gn = sqrtf(1.0f - rel);
    const bool isj0 = (l == 0);
    const float cA = isj0 ? gn : a;

    float prev = 0.f, nbr_prev = 0.f, vlast = 0.f;
    int t = -l;                            // lane's timestep; advances every STEP

    const int vbase = l << 2;
    const int vtop  = NSLOT * 256 + vbase;
    int vaddr = ((NSLOT - l) % NSLOT) * 256 + vbase;   // slot (t mod 96), col l

    int sb = 0;                            // ring slot base of next chunk to read
    float* ochunk = out + (size_t)b * (TT * FF * HH) + (size_t)f * HH;
    float4 gA0, gA1, gA2, gA3, gB0, gB1, gB2, gB3;
    float *opA = nullptr, *opB = nullptr;

    // pair 0 (k=0..63): masked ramp-in, ring fills, no flush
    HALF(ua[0], 0, true, NOPT, NOPT);
    HALF(ua[0], 1, true, NOPT, NOPT);

    // pair 1 (k=64..127): first read at k=86 (chunk 0), then steady pattern
    HALF(ua[1], 0, false, NOPT, PT_RD_A);
    HALF(ua[1], 1, false, PT_AB, PT_BA);

    // pairs 2..7 (k=128..511): steady state, 4 chunks per pair
    PAIR_STEADY(ua[2]);
    PAIR_STEADY(ua[3]);
    PAIR_STEADY(ua[4]);
    PAIR_STEADY(ua[5]);
    PAIR_STEADY(ua[6]);
    PAIR_STEADY(ua[7]);

    // pair 8 (k=512..575): masked ramp-out; flushes chunks 27..30 (u unused by live lanes)
    HALF(ua[7], 0, true, PT_AB, PT_BA);
    HALF(ua[7], 1, true, PT_AB, PT_BA);

    // post-loop: store chunk 30 (in A), then read+store chunk 31 (all writes done)
    STORES(gA0, gA1, gA2, gA3, opA);
    READS(gB0, gB1, gB2, gB3, opB);
    STORES(gB0, gB1, gB2, gB3, opB);

    // h_final = y[T-1][l] (frozen in prev)
    out[(size_t)BB * TT * FF * HH + ((size_t)f * BB + b) * HH + l] = prev;
}

extern "C" void kernel_launch(void* const* d_in, const int* in_sizes, int n_in,
                              void* d_out, int out_size, void* d_ws, size_t ws_size,
                              hipStream_t stream) {
    const float* x     = (const float*)d_in[0];
    const float* W     = (const float*)d_in[1];
    const float* relax = (const float*)d_in[2];
    float* out = (float*)d_out;
    lru_kernel<<<dim3(2048), dim3(64), 0, stream>>>(x, W, relax, out);
}